// Round 4
// baseline (185.742 us; speedup 1.0000x reference)
//
#include <hip/hip_runtime.h>
#include <hip/hip_cooperative_groups.h>

namespace cg = cooperative_groups;

typedef short s8v __attribute__((ext_vector_type(8)));
typedef float f4v __attribute__((ext_vector_type(4)));
typedef unsigned short u16;
typedef unsigned int   u32;
typedef unsigned long long u64;

#define NHEAD 8
#define FDIM  32   // D/2

__device__ __forceinline__ float bf2f(u16 b) {
    return __uint_as_float(((u32)b) << 16);
}
__device__ __forceinline__ u16 f2bf(float f) {
    u32 u = __float_as_uint(f);
    u32 r = u + 0x7fffu + ((u >> 16) & 1u);   // round-to-nearest-even
    return (u16)(r >> 16);
}

// Per-wave dtype detection; all 64 lanes must be active.
__device__ __forceinline__ void detect_wave(const void* W1p, const void* maskp,
                                            const void* eidxp, int lane,
                                            int& isbf, int& mbyte, int& i64f) {
    u32 w1w = ((const u32*)W1p)[lane];
    u32 e = (w1w >> 7) & 0xFFu;
    u64 bE = __ballot(e >= 0x70u && e <= 0x7Fu);
    isbf = (__popcll(bE) > 32) ? 1 : 0;
    u32 mkw = ((const u32*)maskp)[lane];
    u64 bM = __ballot(mkw > 1u);
    mbyte = (bM != 0ull) ? 1 : 0;
    u32 od = ((const u32*)eidxp)[2 * lane + 1];
    u64 bI = __ballot(od != 0u);
    i64f = (bI == 0ull) ? 1 : 0;
}

struct WaveCtx {
    s8v bfrag[2][2];
    float sumWh, b2v, b1c0, b1c1, w2c0, w2c1;
    float wh0, wh1, wh2, wh3;
};

__device__ __forceinline__ WaveCtx setup_wave(int isbf, int lane,
    const void* W1p, const void* b1p, const void* W2p, const void* b2p, const void* Whp)
{
    WaveCtx w;
    const int c0 = lane & 15, c1 = c0 + 16;
    const int krow = (lane >> 4) * 8;
    const int hi4  = (lane >> 4) & 1;
    float WhV[NHEAD]; w.sumWh = 0.f;
    if (isbf) {
        const u16* w1 = (const u16*)W1p; const u16* b1 = (const u16*)b1p;
        const u16* w2 = (const u16*)W2p; const u16* b2 = (const u16*)b2p;
        const u16* wh = (const u16*)Whp;
        #pragma unroll
        for (int h = 0; h < NHEAD; ++h) { WhV[h] = bf2f(wh[h]); w.sumWh += WhV[h]; }
        w.b2v = bf2f(b2[0]);
        w.b1c0 = bf2f(b1[c0]); w.b1c1 = bf2f(b1[c1]);
        w.w2c0 = bf2f(w2[c0]); w.w2c1 = bf2f(w2[c1]);
        #pragma unroll
        for (int cb = 0; cb < 2; ++cb)
            #pragma unroll
            for (int kh = 0; kh < 2; ++kh)
                #pragma unroll
                for (int j = 0; j < 8; ++j) {
                    int k = kh * 32 + krow + j;
                    w.bfrag[cb][kh][j] = (short)w1[k * FDIM + cb * 16 + c0];
                }
    } else {
        const float* w1 = (const float*)W1p; const float* b1 = (const float*)b1p;
        const float* w2 = (const float*)W2p; const float* b2 = (const float*)b2p;
        const float* wh = (const float*)Whp;
        #pragma unroll
        for (int h = 0; h < NHEAD; ++h) { WhV[h] = wh[h]; w.sumWh += WhV[h]; }
        w.b2v = b2[0];
        w.b1c0 = b1[c0]; w.b1c1 = b1[c1];
        w.w2c0 = w2[c0]; w.w2c1 = w2[c1];
        #pragma unroll
        for (int cb = 0; cb < 2; ++cb)
            #pragma unroll
            for (int kh = 0; kh < 2; ++kh)
                #pragma unroll
                for (int j = 0; j < 8; ++j) {
                    int k = kh * 32 + krow + j;
                    w.bfrag[cb][kh][j] = (short)f2bf(w1[k * FDIM + cb * 16 + c0]);
                }
    }
    w.wh0 = hi4 ? WhV[4] : WhV[0];
    w.wh1 = hi4 ? WhV[5] : WhV[1];
    w.wh2 = hi4 ? WhV[6] : WhV[2];
    w.wh3 = hi4 ? WhV[7] : WhV[3];
    return w;
}

__device__ __forceinline__ void load_tile(int isbf, const u16* a16, const float* a32,
                                          int edge, int row, int krow, s8v& a0, s8v& a1)
{
    const size_t rowbase = ((size_t)edge * 8 + (size_t)(row & 7)) * 64 + (size_t)krow;
    if (isbf) {
        a0 = *(const s8v*)(a16 + rowbase);
        a1 = *(const s8v*)(a16 + rowbase + 32);
    } else {
        const float* p = a32 + rowbase;
        #pragma unroll
        for (int j = 0; j < 8; ++j) a0[j] = (short)f2bf(p[j]);
        #pragma unroll
        for (int j = 0; j < 8; ++j) a1[j] = (short)f2bf(p[32 + j]);
    }
}

__device__ __forceinline__ void tile_compute_scatter(const WaveCtx& w, int isbf, int i64f,
    const s8v& a0, const s8v& a1, int ea, int eb, bool hasB,
    const void* pos, const int* e32, const long long* e64, int E,
    float* agg, int lane)
{
    f4v C0 = {0.f,0.f,0.f,0.f}, C1 = {0.f,0.f,0.f,0.f};
    C0 = __builtin_amdgcn_mfma_f32_16x16x32_bf16(a0, w.bfrag[0][0], C0, 0, 0, 0);
    C0 = __builtin_amdgcn_mfma_f32_16x16x32_bf16(a1, w.bfrag[0][1], C0, 0, 0, 0);
    C1 = __builtin_amdgcn_mfma_f32_16x16x32_bf16(a0, w.bfrag[1][0], C1, 0, 0, 0);
    C1 = __builtin_amdgcn_mfma_f32_16x16x32_bf16(a1, w.bfrag[1][1], C1, 0, 0, 0);

    float partial;
    {
        float x0, x1, trow;
        x0 = C0[0] + w.b1c0; x0 = (x0 >= 0.f) ? x0 : 0.01f * x0;
        x1 = C1[0] + w.b1c1; x1 = (x1 >= 0.f) ? x1 : 0.01f * x1;
        trow = x0 * w.w2c0 + x1 * w.w2c1; partial  = trow * w.wh0;
        x0 = C0[1] + w.b1c0; x0 = (x0 >= 0.f) ? x0 : 0.01f * x0;
        x1 = C1[1] + w.b1c1; x1 = (x1 >= 0.f) ? x1 : 0.01f * x1;
        trow = x0 * w.w2c0 + x1 * w.w2c1; partial += trow * w.wh1;
        x0 = C0[2] + w.b1c0; x0 = (x0 >= 0.f) ? x0 : 0.01f * x0;
        x1 = C1[2] + w.b1c1; x1 = (x1 >= 0.f) ? x1 : 0.01f * x1;
        trow = x0 * w.w2c0 + x1 * w.w2c1; partial += trow * w.wh2;
        x0 = C0[3] + w.b1c0; x0 = (x0 >= 0.f) ? x0 : 0.01f * x0;
        x1 = C1[3] + w.b1c1; x1 = (x1 >= 0.f) ? x1 : 0.01f * x1;
        trow = x0 * w.w2c0 + x1 * w.w2c1; partial += trow * w.wh3;
    }
    partial += __shfl_xor(partial, 1);
    partial += __shfl_xor(partial, 2);
    partial += __shfl_xor(partial, 4);
    partial += __shfl_xor(partial, 8);
    partial += __shfl_xor(partial, 16);
    const float att = partial + w.b2v * w.sumWh;

    if ((lane & 31) == 0) {
        const int which = lane >> 5;
        if (!which || hasB) {
            const int e = which ? eb : ea;
            const int s = i64f ? (int)e64[e]     : e32[e];
            const int d = i64f ? (int)e64[E + e] : e32[E + e];
            float px, py, pz, qx, qy, qz;
            if (isbf) {
                const u16* pp = (const u16*)pos;
                px = bf2f(pp[3 * s]); py = bf2f(pp[3 * s + 1]); pz = bf2f(pp[3 * s + 2]);
                qx = bf2f(pp[3 * d]); qy = bf2f(pp[3 * d + 1]); qz = bf2f(pp[3 * d + 2]);
            } else {
                const float* pp = (const float*)pos;
                px = pp[3 * s]; py = pp[3 * s + 1]; pz = pp[3 * s + 2];
                qx = pp[3 * d]; qy = pp[3 * d + 1]; qz = pp[3 * d + 2];
            }
            float dx = px - qx, dy = py - qy, dz = pz - qz;
            float nrm = sqrtf(dx * dx + dy * dy + dz * dz) + 1e-6f;
            float sc = att / nrm;
            atomicAdd(&agg[3 * s + 0], dx * sc);
            atomicAdd(&agg[3 * s + 1], dy * sc);
            atomicAdd(&agg[3 * s + 2], dz * sc);
        }
    }
}

// Phase 1 over chunk range [gw, nchunks) stride nw. All waves fully active.
__device__ __forceinline__ void run_phase1(int isbf, int mbyte, int i64f, int lane,
    int gw, int nw,
    const void* a_ij, const void* pos, const void* eidx, const void* maskp, int pro,
    const WaveCtx& w, float* agg, int E)
{
    const u16*   a16 = (const u16*)a_ij;
    const float* a32 = (const float*)a_ij;
    const int*   e32 = (const int*)eidx;
    const long long* e64 = (const long long*)eidx;
    const unsigned char* m8 = (const unsigned char*)maskp;
    const int*   m32 = (const int*)maskp;

    const int krow = (lane >> 4) * 8;
    const int row  = lane & 15;
    const int nchunks = (E + 127) >> 7;

    for (int c = gw; c < nchunks; c += nw) {
        const int base = c << 7;
        const int ia = base + lane, ib = base + 64 + lane;
        bool va = false, vb = false;
        if (ia < E) {
            int src = i64f ? (int)e64[ia] : e32[ia];
            int mk  = mbyte ? (int)m8[ia] : m32[ia];
            va = (src >= pro) && (mk == 0);
        }
        if (ib < E) {
            int src = i64f ? (int)e64[ib] : e32[ib];
            int mk  = mbyte ? (int)m8[ib] : m32[ib];
            vb = (src >= pro) && (mk == 0);
        }
        u64 m0 = __ballot(va), m1 = __ballot(vb);

        auto pop = [&](int& dst) -> bool {
            if (m0) { int b = __builtin_ctzll(m0); m0 &= m0 - 1; dst = base + b; return true; }
            if (m1) { int b = __builtin_ctzll(m1); m1 &= m1 - 1; dst = base + 64 + b; return true; }
            return false;
        };

        while (m0 | m1) {
            int ea, eb, ec, ed;
            pop(ea);
            bool hB = pop(eb); if (!hB) eb = ea;
            bool hC = pop(ec);
            bool hD = false;
            if (hC) { hD = pop(ed); if (!hD) ed = ec; }

            // issue both tiles' loads before either tile's MFMAs
            s8v a0, a1, b0, b1;
            load_tile(isbf, a16, a32, (row < 8) ? ea : eb, row, krow, a0, a1);
            if (hC) load_tile(isbf, a16, a32, (row < 8) ? ec : ed, row, krow, b0, b1);

            tile_compute_scatter(w, isbf, i64f, a0, a1, ea, eb, hB,
                                 pos, e32, e64, E, agg, lane);
            if (hC)
                tile_compute_scatter(w, isbf, i64f, b0, b1, ec, ed, hD,
                                     pos, e32, e64, E, agg, lane);
        }
    }
}

__device__ __forceinline__ void run_phase2(int isbf, int i64f,
    const void* pos, const void* gidxp, const float* agg, void* outp,
    int g0, int gstride, int G)
{
    for (int g = g0; g < G; g += gstride) {
        const int idx = i64f ? (int)((const long long*)gidxp)[g] : ((const int*)gidxp)[g];
        #pragma unroll
        for (int c = 0; c < 3; ++c) {
            float p;
            if (isbf) p = bf2f(((const u16*)pos)[3 * idx + c]);
            else      p = ((const float*)pos)[3 * idx + c];
            float v = p + agg[3 * idx + c];
            if (isbf) ((u16*)outp)[3 * g + c] = f2bf(v);
            else      ((float*)outp)[3 * g + c] = v;
        }
    }
}

__global__ __launch_bounds__(256, 4)
void fused_kernel(const void* __restrict__ a_ij,
                  const void* __restrict__ pos,
                  const void* __restrict__ eidx,
                  const void* __restrict__ maskp,
                  const int*  __restrict__ proP,
                  const void* __restrict__ W1p,
                  const void* __restrict__ b1p,
                  const void* __restrict__ W2p,
                  const void* __restrict__ b2p,
                  const void* __restrict__ Whp,
                  const void* __restrict__ gidxp,
                  void* __restrict__ outp,
                  float* __restrict__ agg,
                  int E, int N3, int G)
{
    cg::grid_group grid = cg::this_grid();

    const int lane = threadIdx.x & 63;
    int isbf, mbyte, i64f;
    detect_wave(W1p, maskp, eidx, lane, isbf, mbyte, i64f);

    const int gtid = blockIdx.x * blockDim.x + threadIdx.x;
    const int gsz  = gridDim.x * blockDim.x;

    for (int i = gtid; i < N3; i += gsz) agg[i] = 0.f;

    const WaveCtx w = setup_wave(isbf, lane, W1p, b1p, W2p, b2p, Whp);
    const int pro = proP[0];

    grid.sync();

    run_phase1(isbf, mbyte, i64f, lane, gtid >> 6, gsz >> 6,
               a_ij, pos, eidx, maskp, pro, w, agg, E);

    grid.sync();

    run_phase2(isbf, i64f, pos, gidxp, agg, outp, gtid, gsz, G);
}

// ---------- fallback path (3 nodes) ----------
__global__ __launch_bounds__(256)
void attn_fb(const void* __restrict__ a_ij,
             const void* __restrict__ pos,
             const void* __restrict__ eidx,
             const void* __restrict__ maskp,
             const int*  __restrict__ proP,
             const void* __restrict__ W1p,
             const void* __restrict__ b1p,
             const void* __restrict__ W2p,
             const void* __restrict__ b2p,
             const void* __restrict__ Whp,
             float* __restrict__ agg,
             int E)
{
    const int lane = threadIdx.x & 63;
    int isbf, mbyte, i64f;
    detect_wave(W1p, maskp, eidx, lane, isbf, mbyte, i64f);
    const WaveCtx w = setup_wave(isbf, lane, W1p, b1p, W2p, b2p, Whp);
    const int pro = proP[0];
    const int gtid = blockIdx.x * blockDim.x + threadIdx.x;
    const int gsz  = gridDim.x * blockDim.x;
    run_phase1(isbf, mbyte, i64f, lane, gtid >> 6, gsz >> 6,
               a_ij, pos, eidx, maskp, pro, w, agg, E);
}

__global__ __launch_bounds__(256)
void finalize_fb(const void* __restrict__ pos,
                 const void* __restrict__ gidxp,
                 const float* __restrict__ agg,
                 void* __restrict__ outp,
                 const void* __restrict__ W1p,
                 const void* __restrict__ maskp,
                 const void* __restrict__ eidxp,
                 int G)
{
    const int lane = threadIdx.x & 63;
    int isbf, mbyte, i64f;
    detect_wave(W1p, maskp, eidxp, lane, isbf, mbyte, i64f);
    (void)mbyte;
    int g = blockIdx.x * blockDim.x + threadIdx.x;
    if (g >= G) return;
    run_phase2(isbf, i64f, pos, gidxp, agg, outp, g, 1 << 30, G);
}

extern "C" void kernel_launch(void* const* d_in, const int* in_sizes, int n_in,
                              void* d_out, int out_size, void* d_ws, size_t ws_size,
                              hipStream_t stream) {
    const void* a_ij = d_in[0];
    const void* pos  = d_in[1];
    const void* eidx = d_in[3];
    const void* gidx = d_in[5];
    const void* mask = d_in[6];
    const int*  pro  = (const int*)d_in[7];
    const void* W1   = d_in[8];
    const void* b1   = d_in[9];
    const void* W2   = d_in[10];
    const void* b2   = d_in[11];
    const void* Wh   = d_in[12];

    int E  = in_sizes[3] / 2;
    int N3 = (in_sizes[1] / 3) * 3;
    int G  = in_sizes[5];
    float* agg = (float*)d_ws;

    // Cooperative grid sized from the runtime's occupancy answer.
    int maxB = 0;
    hipError_t eOcc = hipOccupancyMaxActiveBlocksPerMultiprocessor(
        &maxB, (const void*)fused_kernel, 256, 0);
    int dev = 0; hipGetDevice(&dev);
    int cus = 0;
    hipDeviceGetAttribute(&cus, hipDeviceAttributeMultiprocessorCount, dev);
    if (cus <= 0) cus = 256;
    if (eOcc != hipSuccess || maxB < 1) maxB = 1;
    long long gridL = (long long)maxB * (long long)cus;
    if (gridL > 2048) gridL = 2048;
    unsigned int grid = (unsigned int)gridL;

    void* args[] = {
        (void*)&a_ij, (void*)&pos, (void*)&eidx, (void*)&mask, (void*)&pro,
        (void*)&W1, (void*)&b1, (void*)&W2, (void*)&b2, (void*)&Wh,
        (void*)&gidx, (void*)&d_out, (void*)&agg, (void*)&E, (void*)&N3, (void*)&G
    };
    hipError_t err = hipLaunchCooperativeKernel((const void*)fused_kernel,
                                                dim3(grid), dim3(256),
                                                args, 0, stream);
    if (err != hipSuccess) {
        // fallback: proven 3-node path
        hipMemsetAsync(agg, 0, (size_t)N3 * sizeof(float), stream);
        attn_fb<<<2048, 256, 0, stream>>>(a_ij, pos, eidx, mask, pro,
                                          W1, b1, W2, b2, Wh, agg, E);
        finalize_fb<<<(G + 255) / 256, 256, 0, stream>>>(pos, gidx, agg, d_out,
                                                         W1, mask, eidx, G);
    }
}

// Round 5
// 47.059 us; speedup vs baseline: 3.9470x; 3.9470x over previous
//
#include <hip/hip_runtime.h>

typedef short s8v __attribute__((ext_vector_type(8)));
typedef float f4v __attribute__((ext_vector_type(4)));
typedef unsigned short u16;
typedef unsigned int   u32;
typedef unsigned long long u64;

#define NHEAD 8
#define FDIM  32   // D/2

__device__ __forceinline__ float bf2f(u16 b) {
    return __uint_as_float(((u32)b) << 16);
}
__device__ __forceinline__ u16 f2bf(float f) {
    u32 u = __float_as_uint(f);
    u32 r = u + 0x7fffu + ((u >> 16) & 1u);   // round-to-nearest-even
    return (u16)(r >> 16);
}

// Per-wave dtype detection; all 64 lanes must be active.
__device__ __forceinline__ void detect_wave(const void* W1p, const void* maskp,
                                            const void* eidxp, int lane,
                                            int& isbf, int& mbyte, int& i64f) {
    u32 w1w = ((const u32*)W1p)[lane];
    u32 e = (w1w >> 7) & 0xFFu;
    u64 bE = __ballot(e >= 0x70u && e <= 0x7Fu);
    isbf = (__popcll(bE) > 32) ? 1 : 0;
    u32 mkw = ((const u32*)maskp)[lane];
    u64 bM = __ballot(mkw > 1u);
    mbyte = (bM != 0ull) ? 1 : 0;
    u32 od = ((const u32*)eidxp)[2 * lane + 1];
    u64 bI = __ballot(od != 0u);
    i64f = (bI == 0ull) ? 1 : 0;
}

struct WaveCtx {
    s8v bfrag[2][2];
    float sumWh, b2v, b1c0, b1c1, w2c0, w2c1;
    float wh0, wh1, wh2, wh3;
};

__device__ __forceinline__ WaveCtx setup_wave(int isbf, int lane,
    const void* W1p, const void* b1p, const void* W2p, const void* b2p, const void* Whp)
{
    WaveCtx w;
    const int c0 = lane & 15, c1 = c0 + 16;
    const int krow = (lane >> 4) * 8;
    const int hi4  = (lane >> 4) & 1;
    float WhV[NHEAD]; w.sumWh = 0.f;
    if (isbf) {
        const u16* w1 = (const u16*)W1p; const u16* b1 = (const u16*)b1p;
        const u16* w2 = (const u16*)W2p; const u16* b2 = (const u16*)b2p;
        const u16* wh = (const u16*)Whp;
        #pragma unroll
        for (int h = 0; h < NHEAD; ++h) { WhV[h] = bf2f(wh[h]); w.sumWh += WhV[h]; }
        w.b2v = bf2f(b2[0]);
        w.b1c0 = bf2f(b1[c0]); w.b1c1 = bf2f(b1[c1]);
        w.w2c0 = bf2f(w2[c0]); w.w2c1 = bf2f(w2[c1]);
        #pragma unroll
        for (int cb = 0; cb < 2; ++cb)
            #pragma unroll
            for (int kh = 0; kh < 2; ++kh)
                #pragma unroll
                for (int j = 0; j < 8; ++j) {
                    int k = kh * 32 + krow + j;
                    w.bfrag[cb][kh][j] = (short)w1[k * FDIM + cb * 16 + c0];
                }
    } else {
        const float* w1 = (const float*)W1p; const float* b1 = (const float*)b1p;
        const float* w2 = (const float*)W2p; const float* b2 = (const float*)b2p;
        const float* wh = (const float*)Whp;
        #pragma unroll
        for (int h = 0; h < NHEAD; ++h) { WhV[h] = wh[h]; w.sumWh += WhV[h]; }
        w.b2v = b2[0];
        w.b1c0 = b1[c0]; w.b1c1 = b1[c1];
        w.w2c0 = w2[c0]; w.w2c1 = w2[c1];
        #pragma unroll
        for (int cb = 0; cb < 2; ++cb)
            #pragma unroll
            for (int kh = 0; kh < 2; ++kh)
                #pragma unroll
                for (int j = 0; j < 8; ++j) {
                    int k = kh * 32 + krow + j;
                    w.bfrag[cb][kh][j] = (short)f2bf(w1[k * FDIM + cb * 16 + c0]);
                }
    }
    w.wh0 = hi4 ? WhV[4] : WhV[0];
    w.wh1 = hi4 ? WhV[5] : WhV[1];
    w.wh2 = hi4 ? WhV[6] : WhV[2];
    w.wh3 = hi4 ? WhV[7] : WhV[3];
    return w;
}

__device__ __forceinline__ void load_tile(int isbf, const u16* a16, const float* a32,
                                          int edge, int row, int krow, s8v& a0, s8v& a1)
{
    const size_t rowbase = ((size_t)edge * 8 + (size_t)(row & 7)) * 64 + (size_t)krow;
    if (isbf) {
        a0 = *(const s8v*)(a16 + rowbase);          // 16 B
        a1 = *(const s8v*)(a16 + rowbase + 32);     // 16 B
    } else {
        const f4v* p = (const f4v*)(a32 + rowbase); // 32-B aligned
        f4v v0 = p[0], v1 = p[1], v2 = p[8], v3 = p[9];
        #pragma unroll
        for (int j = 0; j < 4; ++j) {
            a0[j]     = (short)f2bf(v0[j]);
            a0[j + 4] = (short)f2bf(v1[j]);
            a1[j]     = (short)f2bf(v2[j]);
            a1[j + 4] = (short)f2bf(v3[j]);
        }
    }
}

__device__ __forceinline__ void tile_compute_scatter(const WaveCtx& w, int isbf, int i64f,
    const s8v& a0, const s8v& a1, int ea, int eb, bool hasB,
    const void* pos, const int* e32, const long long* e64, int E,
    float* agg, int lane)
{
    f4v C0 = {0.f,0.f,0.f,0.f}, C1 = {0.f,0.f,0.f,0.f};
    C0 = __builtin_amdgcn_mfma_f32_16x16x32_bf16(a0, w.bfrag[0][0], C0, 0, 0, 0);
    C0 = __builtin_amdgcn_mfma_f32_16x16x32_bf16(a1, w.bfrag[0][1], C0, 0, 0, 0);
    C1 = __builtin_amdgcn_mfma_f32_16x16x32_bf16(a0, w.bfrag[1][0], C1, 0, 0, 0);
    C1 = __builtin_amdgcn_mfma_f32_16x16x32_bf16(a1, w.bfrag[1][1], C1, 0, 0, 0);

    float partial;
    {
        float x0, x1, trow;
        x0 = C0[0] + w.b1c0; x0 = (x0 >= 0.f) ? x0 : 0.01f * x0;
        x1 = C1[0] + w.b1c1; x1 = (x1 >= 0.f) ? x1 : 0.01f * x1;
        trow = x0 * w.w2c0 + x1 * w.w2c1; partial  = trow * w.wh0;
        x0 = C0[1] + w.b1c0; x0 = (x0 >= 0.f) ? x0 : 0.01f * x0;
        x1 = C1[1] + w.b1c1; x1 = (x1 >= 0.f) ? x1 : 0.01f * x1;
        trow = x0 * w.w2c0 + x1 * w.w2c1; partial += trow * w.wh1;
        x0 = C0[2] + w.b1c0; x0 = (x0 >= 0.f) ? x0 : 0.01f * x0;
        x1 = C1[2] + w.b1c1; x1 = (x1 >= 0.f) ? x1 : 0.01f * x1;
        trow = x0 * w.w2c0 + x1 * w.w2c1; partial += trow * w.wh2;
        x0 = C0[3] + w.b1c0; x0 = (x0 >= 0.f) ? x0 : 0.01f * x0;
        x1 = C1[3] + w.b1c1; x1 = (x1 >= 0.f) ? x1 : 0.01f * x1;
        trow = x0 * w.w2c0 + x1 * w.w2c1; partial += trow * w.wh3;
    }
    partial += __shfl_xor(partial, 1);
    partial += __shfl_xor(partial, 2);
    partial += __shfl_xor(partial, 4);
    partial += __shfl_xor(partial, 8);
    partial += __shfl_xor(partial, 16);
    const float att = partial + w.b2v * w.sumWh;

    if ((lane & 31) == 0) {
        const int which = lane >> 5;
        if (!which || hasB) {
            const int e = which ? eb : ea;
            const int s = i64f ? (int)e64[e]     : e32[e];
            const int d = i64f ? (int)e64[E + e] : e32[E + e];
            float px, py, pz, qx, qy, qz;
            if (isbf) {
                const u16* pp = (const u16*)pos;
                px = bf2f(pp[3 * s]); py = bf2f(pp[3 * s + 1]); pz = bf2f(pp[3 * s + 2]);
                qx = bf2f(pp[3 * d]); qy = bf2f(pp[3 * d + 1]); qz = bf2f(pp[3 * d + 2]);
            } else {
                const float* pp = (const float*)pos;
                px = pp[3 * s]; py = pp[3 * s + 1]; pz = pp[3 * s + 2];
                qx = pp[3 * d]; qy = pp[3 * d + 1]; qz = pp[3 * d + 2];
            }
            float dx = px - qx, dy = py - qy, dz = pz - qz;
            float nrm = sqrtf(dx * dx + dy * dy + dz * dz) + 1e-6f;
            float sc = att / nrm;
            atomicAdd(&agg[3 * s + 0], dx * sc);
            atomicAdd(&agg[3 * s + 1], dy * sc);
            atomicAdd(&agg[3 * s + 2], dz * sc);
        }
    }
}

// K1: zero agg
__global__ __launch_bounds__(256)
void zero_kernel(float* __restrict__ agg, int N3)
{
    int i = blockIdx.x * blockDim.x + threadIdx.x;
    if (i < N3) agg[i] = 0.f;
}

// K2: one 128-edge chunk per wave; ballot-compact; dense MFMA pairs.
__global__ __launch_bounds__(256)
void attn_kernel(const void* __restrict__ a_ij,
                 const void* __restrict__ pos,
                 const void* __restrict__ eidx,
                 const void* __restrict__ maskp,
                 const int*  __restrict__ proP,
                 const void* __restrict__ W1p,
                 const void* __restrict__ b1p,
                 const void* __restrict__ W2p,
                 const void* __restrict__ b2p,
                 const void* __restrict__ Whp,
                 float* __restrict__ agg,
                 int E)
{
    const int lane = threadIdx.x & 63;
    int isbf, mbyte, i64f;
    detect_wave(W1p, maskp, eidx, lane, isbf, mbyte, i64f);

    const int gw = blockIdx.x * (blockDim.x >> 6) + (threadIdx.x >> 6);
    const int nchunks = (E + 127) >> 7;
    if (gw >= nchunks) return;

    const WaveCtx w = setup_wave(isbf, lane, W1p, b1p, W2p, b2p, Whp);
    const int pro = proP[0];

    const u16*   a16 = (const u16*)a_ij;
    const float* a32 = (const float*)a_ij;
    const int*   e32 = (const int*)eidx;
    const long long* e64 = (const long long*)eidx;
    const unsigned char* m8 = (const unsigned char*)maskp;
    const int*   m32 = (const int*)maskp;

    const int krow = (lane >> 4) * 8;
    const int row  = lane & 15;

    const int base = gw << 7;
    const int ia = base + lane, ib = base + 64 + lane;
    bool va = false, vb = false;
    if (ia < E) {
        int src = i64f ? (int)e64[ia] : e32[ia];
        int mk  = mbyte ? (int)m8[ia] : m32[ia];
        va = (src >= pro) && (mk == 0);
    }
    if (ib < E) {
        int src = i64f ? (int)e64[ib] : e32[ib];
        int mk  = mbyte ? (int)m8[ib] : m32[ib];
        vb = (src >= pro) && (mk == 0);
    }
    u64 m0 = __ballot(va), m1 = __ballot(vb);

    auto pop = [&](int& dst) -> bool {
        if (m0) { int b = __builtin_ctzll(m0); m0 &= m0 - 1; dst = base + b; return true; }
        if (m1) { int b = __builtin_ctzll(m1); m1 &= m1 - 1; dst = base + 64 + b; return true; }
        return false;
    };

    while (m0 | m1) {
        int ea, eb, ec, ed;
        pop(ea);
        bool hB = pop(eb); if (!hB) eb = ea;
        bool hC = pop(ec);
        bool hD = false;
        if (hC) { hD = pop(ed); if (!hD) ed = ec; }

        // issue both tiles' loads before either tile's MFMAs
        s8v a0, a1, b0, b1;
        load_tile(isbf, a16, a32, (row < 8) ? ea : eb, row, krow, a0, a1);
        if (hC) load_tile(isbf, a16, a32, (row < 8) ? ec : ed, row, krow, b0, b1);

        tile_compute_scatter(w, isbf, i64f, a0, a1, ea, eb, hB,
                             pos, e32, e64, E, agg, lane);
        if (hC)
            tile_compute_scatter(w, isbf, i64f, b0, b1, ec, ed, hD,
                                 pos, e32, e64, E, agg, lane);
    }
}

// K3: finalize
__global__ __launch_bounds__(256)
void finalize_kernel(const void* __restrict__ pos,
                     const void* __restrict__ gidxp,
                     const float* __restrict__ agg,
                     void* __restrict__ outp,
                     const void* __restrict__ W1p,
                     const void* __restrict__ maskp,
                     const void* __restrict__ eidxp,
                     int G)
{
    const int lane = threadIdx.x & 63;
    int isbf, mbyte, i64f;
    detect_wave(W1p, maskp, eidxp, lane, isbf, mbyte, i64f);
    (void)mbyte;

    int g = blockIdx.x * blockDim.x + threadIdx.x;
    if (g >= G) return;
    const int idx = i64f ? (int)((const long long*)gidxp)[g] : ((const int*)gidxp)[g];
    #pragma unroll
    for (int c = 0; c < 3; ++c) {
        float p;
        if (isbf) p = bf2f(((const u16*)pos)[3 * idx + c]);
        else      p = ((const float*)pos)[3 * idx + c];
        float v = p + agg[3 * idx + c];
        if (isbf) ((u16*)outp)[3 * g + c] = f2bf(v);
        else      ((float*)outp)[3 * g + c] = v;
    }
}

extern "C" void kernel_launch(void* const* d_in, const int* in_sizes, int n_in,
                              void* d_out, int out_size, void* d_ws, size_t ws_size,
                              hipStream_t stream) {
    const void* a_ij = d_in[0];
    const void* pos  = d_in[1];
    const void* eidx = d_in[3];
    const void* gidx = d_in[5];
    const void* mask = d_in[6];
    const int*  pro  = (const int*)d_in[7];
    const void* W1   = d_in[8];
    const void* b1   = d_in[9];
    const void* W2   = d_in[10];
    const void* b2   = d_in[11];
    const void* Wh   = d_in[12];

    const int E  = in_sizes[3] / 2;
    const int N3 = (in_sizes[1] / 3) * 3;
    const int G  = in_sizes[5];
    float* agg = (float*)d_ws;

    zero_kernel<<<(N3 + 255) / 256, 256, 0, stream>>>(agg, N3);

    const int nchunks = (E + 127) >> 7;           // one 128-edge chunk per wave
    const int nblocks = (nchunks + 3) / 4;        // 4 waves per block
    attn_kernel<<<nblocks, 256, 0, stream>>>(a_ij, pos, eidx, mask, pro,
                                             W1, b1, W2, b2, Wh, agg, E);

    finalize_kernel<<<(G + 255) / 256, 256, 0, stream>>>(pos, gidx, agg, d_out,
                                                         W1, mask, eidx, G);
}

// Round 6
// 42.635 us; speedup vs baseline: 4.3565x; 1.1038x over previous
//
#include <hip/hip_runtime.h>

typedef short s8v __attribute__((ext_vector_type(8)));
typedef float f4v __attribute__((ext_vector_type(4)));
typedef unsigned short u16;
typedef unsigned int   u32;
typedef unsigned long long u64;

#define NHEAD 8
#define FDIM  32   // D/2

__device__ __forceinline__ float bf2f(u16 b) {
    return __uint_as_float(((u32)b) << 16);
}
__device__ __forceinline__ u16 f2bf(float f) {
    u32 u = __float_as_uint(f);
    u32 r = u + 0x7fffu + ((u >> 16) & 1u);   // round-to-nearest-even
    return (u16)(r >> 16);
}

// Per-wave dtype detection; all 64 lanes must be active.
__device__ __forceinline__ void detect_wave(const void* W1p, const void* maskp,
                                            const void* eidxp, int lane,
                                            int& isbf, int& mbyte, int& i64f) {
    u32 w1w = ((const u32*)W1p)[lane];
    u32 e = (w1w >> 7) & 0xFFu;
    u64 bE = __ballot(e >= 0x70u && e <= 0x7Fu);
    isbf = (__popcll(bE) > 32) ? 1 : 0;
    u32 mkw = ((const u32*)maskp)[lane];
    u64 bM = __ballot(mkw > 1u);
    mbyte = (bM != 0ull) ? 1 : 0;
    u32 od = ((const u32*)eidxp)[2 * lane + 1];
    u64 bI = __ballot(od != 0u);
    i64f = (bI == 0ull) ? 1 : 0;
}

struct WaveCtx {
    s8v bfrag[2][2];
    float sumWh, b2v, b1c0, b1c1, w2c0, w2c1;
    float wh0, wh1, wh2, wh3;
};

__device__ __forceinline__ WaveCtx setup_wave(int isbf, int lane,
    const void* W1p, const void* b1p, const void* W2p, const void* b2p, const void* Whp)
{
    WaveCtx w;
    const int c0 = lane & 15, c1 = c0 + 16;
    const int krow = (lane >> 4) * 8;
    const int hi4  = (lane >> 4) & 1;
    float WhV[NHEAD]; w.sumWh = 0.f;
    if (isbf) {
        const u16* w1 = (const u16*)W1p; const u16* b1 = (const u16*)b1p;
        const u16* w2 = (const u16*)W2p; const u16* b2 = (const u16*)b2p;
        const u16* wh = (const u16*)Whp;
        #pragma unroll
        for (int h = 0; h < NHEAD; ++h) { WhV[h] = bf2f(wh[h]); w.sumWh += WhV[h]; }
        w.b2v = bf2f(b2[0]);
        w.b1c0 = bf2f(b1[c0]); w.b1c1 = bf2f(b1[c1]);
        w.w2c0 = bf2f(w2[c0]); w.w2c1 = bf2f(w2[c1]);
        #pragma unroll
        for (int cb = 0; cb < 2; ++cb)
            #pragma unroll
            for (int kh = 0; kh < 2; ++kh)
                #pragma unroll
                for (int j = 0; j < 8; ++j) {
                    int k = kh * 32 + krow + j;
                    w.bfrag[cb][kh][j] = (short)w1[k * FDIM + cb * 16 + c0];
                }
    } else {
        const float* w1 = (const float*)W1p; const float* b1 = (const float*)b1p;
        const float* w2 = (const float*)W2p; const float* b2 = (const float*)b2p;
        const float* wh = (const float*)Whp;
        #pragma unroll
        for (int h = 0; h < NHEAD; ++h) { WhV[h] = wh[h]; w.sumWh += WhV[h]; }
        w.b2v = b2[0];
        w.b1c0 = b1[c0]; w.b1c1 = b1[c1];
        w.w2c0 = w2[c0]; w.w2c1 = w2[c1];
        #pragma unroll
        for (int cb = 0; cb < 2; ++cb)
            #pragma unroll
            for (int kh = 0; kh < 2; ++kh)
                #pragma unroll
                for (int j = 0; j < 8; ++j) {
                    int k = kh * 32 + krow + j;
                    w.bfrag[cb][kh][j] = (short)f2bf(w1[k * FDIM + cb * 16 + c0]);
                }
    }
    w.wh0 = hi4 ? WhV[4] : WhV[0];
    w.wh1 = hi4 ? WhV[5] : WhV[1];
    w.wh2 = hi4 ? WhV[6] : WhV[2];
    w.wh3 = hi4 ? WhV[7] : WhV[3];
    return w;
}

__device__ __forceinline__ void load_tile(int isbf, const u16* a16, const float* a32,
                                          int edge, int row, int krow, s8v& a0, s8v& a1)
{
    const size_t rowbase = ((size_t)edge * 8 + (size_t)(row & 7)) * 64 + (size_t)krow;
    if (isbf) {
        a0 = *(const s8v*)(a16 + rowbase);          // 16 B
        a1 = *(const s8v*)(a16 + rowbase + 32);     // 16 B
    } else {
        const f4v* p = (const f4v*)(a32 + rowbase); // 32-B aligned
        f4v v0 = p[0], v1 = p[1], v2 = p[8], v3 = p[9];
        #pragma unroll
        for (int j = 0; j < 4; ++j) {
            a0[j]     = (short)f2bf(v0[j]);
            a0[j + 4] = (short)f2bf(v1[j]);
            a1[j]     = (short)f2bf(v2[j]);
            a1[j + 4] = (short)f2bf(v3[j]);
        }
    }
}

// MFMA + MLP epilogue; returns att valid in ALL lanes (per 32-half's edge).
__device__ __forceinline__ float tile_att(const WaveCtx& w, const s8v& a0, const s8v& a1)
{
    f4v C0 = {0.f,0.f,0.f,0.f}, C1 = {0.f,0.f,0.f,0.f};
    C0 = __builtin_amdgcn_mfma_f32_16x16x32_bf16(a0, w.bfrag[0][0], C0, 0, 0, 0);
    C0 = __builtin_amdgcn_mfma_f32_16x16x32_bf16(a1, w.bfrag[0][1], C0, 0, 0, 0);
    C1 = __builtin_amdgcn_mfma_f32_16x16x32_bf16(a0, w.bfrag[1][0], C1, 0, 0, 0);
    C1 = __builtin_amdgcn_mfma_f32_16x16x32_bf16(a1, w.bfrag[1][1], C1, 0, 0, 0);

    float partial;
    {
        float x0, x1, trow;
        x0 = C0[0] + w.b1c0; x0 = (x0 >= 0.f) ? x0 : 0.01f * x0;
        x1 = C1[0] + w.b1c1; x1 = (x1 >= 0.f) ? x1 : 0.01f * x1;
        trow = x0 * w.w2c0 + x1 * w.w2c1; partial  = trow * w.wh0;
        x0 = C0[1] + w.b1c0; x0 = (x0 >= 0.f) ? x0 : 0.01f * x0;
        x1 = C1[1] + w.b1c1; x1 = (x1 >= 0.f) ? x1 : 0.01f * x1;
        trow = x0 * w.w2c0 + x1 * w.w2c1; partial += trow * w.wh1;
        x0 = C0[2] + w.b1c0; x0 = (x0 >= 0.f) ? x0 : 0.01f * x0;
        x1 = C1[2] + w.b1c1; x1 = (x1 >= 0.f) ? x1 : 0.01f * x1;
        trow = x0 * w.w2c0 + x1 * w.w2c1; partial += trow * w.wh2;
        x0 = C0[3] + w.b1c0; x0 = (x0 >= 0.f) ? x0 : 0.01f * x0;
        x1 = C1[3] + w.b1c1; x1 = (x1 >= 0.f) ? x1 : 0.01f * x1;
        trow = x0 * w.w2c0 + x1 * w.w2c1; partial += trow * w.wh3;
    }
    partial += __shfl_xor(partial, 1);
    partial += __shfl_xor(partial, 2);
    partial += __shfl_xor(partial, 4);
    partial += __shfl_xor(partial, 8);
    partial += __shfl_xor(partial, 16);
    return partial + w.b2v * w.sumWh;
}

// K1: zero agg
__global__ __launch_bounds__(256)
void zero_kernel(float* __restrict__ agg, int N3)
{
    int i = blockIdx.x * blockDim.x + threadIdx.x;
    if (i < N3) agg[i] = 0.f;
}

// K2: one 64-edge chunk per wave; ballot-compact; dense MFMA pairs;
//     deferred all-lane-parallel scatter epilogue.
__global__ __launch_bounds__(256)
void attn_kernel(const void* __restrict__ a_ij,
                 const void* __restrict__ pos,
                 const void* __restrict__ eidx,
                 const void* __restrict__ maskp,
                 const int*  __restrict__ proP,
                 const void* __restrict__ W1p,
                 const void* __restrict__ b1p,
                 const void* __restrict__ W2p,
                 const void* __restrict__ b2p,
                 const void* __restrict__ Whp,
                 float* __restrict__ agg,
                 int E)
{
    __shared__ float attbuf[4][64];

    const int lane = threadIdx.x & 63;
    const int wv   = threadIdx.x >> 6;
    int isbf, mbyte, i64f;
    detect_wave(W1p, maskp, eidx, lane, isbf, mbyte, i64f);

    const int gw = blockIdx.x * 4 + wv;
    const int nchunks = (E + 63) >> 6;
    if (gw >= nchunks) return;

    const WaveCtx w = setup_wave(isbf, lane, W1p, b1p, W2p, b2p, Whp);
    const int pro = proP[0];

    const u16*   a16 = (const u16*)a_ij;
    const float* a32 = (const float*)a_ij;
    const int*   e32 = (const int*)eidx;
    const long long* e64 = (const long long*)eidx;
    const unsigned char* m8 = (const unsigned char*)maskp;
    const int*   m32 = (const int*)maskp;

    const int krow = (lane >> 4) * 8;
    const int row  = lane & 15;

    const int base = gw << 6;
    const int ie = base + lane;
    bool v = false; int srcv = 0;
    if (ie < E) {
        srcv = i64f ? (int)e64[ie] : e32[ie];
        int mk = mbyte ? (int)m8[ie] : m32[ie];
        v = (srcv >= pro) && (mk == 0);
    }
    u64 m0 = __ballot(v);
    const u64 msav = m0;
    const int nv = __popcll(m0);
    if (nv == 0) return;

    auto pop = [&](int& dst) -> bool {
        if (m0) { int b = __builtin_ctzll(m0); m0 &= m0 - 1; dst = b; return true; }
        return false;
    };

    int it = 0;   // pair counter (LDS slot base = 2*it)
    while (m0) {
        int ba, bb, bc, bd;
        pop(ba);
        bool hB = pop(bb); if (!hB) bb = ba;
        bool hC = pop(bc);
        bool hD = false;
        if (hC) { hD = pop(bd); if (!hD) bd = bc; }

        // issue both pairs' loads before any MFMA
        s8v a0, a1, b0, b1;
        load_tile(isbf, a16, a32, base + ((row < 8) ? ba : bb), row, krow, a0, a1);
        if (hC) load_tile(isbf, a16, a32, base + ((row < 8) ? bc : bd), row, krow, b0, b1);

        float attA = tile_att(w, a0, a1);
        if ((lane & 31) == 0) attbuf[wv][2 * it + (lane >> 5)] = attA;
        if (hC) {
            float attB = tile_att(w, b0, b1);
            if ((lane & 31) == 0) attbuf[wv][2 * it + 2 + (lane >> 5)] = attB;
        }
        it += hC ? 2 : 1;
    }

    // order LDS writes before cross-lane reads (same wave, lockstep)
    asm volatile("s_waitcnt lgkmcnt(0)" ::: "memory");

    // ---- parallel epilogue: lane i handles the i-th valid edge ----
    u64 mm = msav;
    #pragma unroll 1
    for (int k = 0; k < lane; ++k) mm &= mm - 1;
    const int bp = mm ? __builtin_ctzll(mm) : 0;     // lane-th set bit (if any)
    const int s  = __shfl(srcv, bp);                  // all lanes active

    if (lane < nv) {
        const float att = attbuf[wv][lane];
        const int e = base + bp;
        const int d = i64f ? (int)e64[E + e] : e32[E + e];
        float px, py, pz, qx, qy, qz;
        if (isbf) {
            const u16* pp = (const u16*)pos;
            px = bf2f(pp[3 * s]); py = bf2f(pp[3 * s + 1]); pz = bf2f(pp[3 * s + 2]);
            qx = bf2f(pp[3 * d]); qy = bf2f(pp[3 * d + 1]); qz = bf2f(pp[3 * d + 2]);
        } else {
            const float* pp = (const float*)pos;
            px = pp[3 * s]; py = pp[3 * s + 1]; pz = pp[3 * s + 2];
            qx = pp[3 * d]; qy = pp[3 * d + 1]; qz = pp[3 * d + 2];
        }
        float dx = px - qx, dy = py - qy, dz = pz - qz;
        float nrm = sqrtf(dx * dx + dy * dy + dz * dz) + 1e-6f;
        float sc = att / nrm;
        atomicAdd(&agg[3 * s + 0], dx * sc);
        atomicAdd(&agg[3 * s + 1], dy * sc);
        atomicAdd(&agg[3 * s + 2], dz * sc);
    }
}

// K3: finalize
__global__ __launch_bounds__(256)
void finalize_kernel(const void* __restrict__ pos,
                     const void* __restrict__ gidxp,
                     const float* __restrict__ agg,
                     void* __restrict__ outp,
                     const void* __restrict__ W1p,
                     const void* __restrict__ maskp,
                     const void* __restrict__ eidxp,
                     int G)
{
    const int lane = threadIdx.x & 63;
    int isbf, mbyte, i64f;
    detect_wave(W1p, maskp, eidxp, lane, isbf, mbyte, i64f);
    (void)mbyte;

    int g = blockIdx.x * blockDim.x + threadIdx.x;
    if (g >= G) return;
    const int idx = i64f ? (int)((const long long*)gidxp)[g] : ((const int*)gidxp)[g];
    #pragma unroll
    for (int c = 0; c < 3; ++c) {
        float p;
        if (isbf) p = bf2f(((const u16*)pos)[3 * idx + c]);
        else      p = ((const float*)pos)[3 * idx + c];
        float v = p + agg[3 * idx + c];
        if (isbf) ((u16*)outp)[3 * g + c] = f2bf(v);
        else      ((float*)outp)[3 * g + c] = v;
    }
}

extern "C" void kernel_launch(void* const* d_in, const int* in_sizes, int n_in,
                              void* d_out, int out_size, void* d_ws, size_t ws_size,
                              hipStream_t stream) {
    const void* a_ij = d_in[0];
    const void* pos  = d_in[1];
    const void* eidx = d_in[3];
    const void* gidx = d_in[5];
    const void* mask = d_in[6];
    const int*  pro  = (const int*)d_in[7];
    const void* W1   = d_in[8];
    const void* b1   = d_in[9];
    const void* W2   = d_in[10];
    const void* b2   = d_in[11];
    const void* Wh   = d_in[12];

    const int E  = in_sizes[3] / 2;
    const int N3 = (in_sizes[1] / 3) * 3;
    const int G  = in_sizes[5];
    float* agg = (float*)d_ws;

    zero_kernel<<<(N3 + 255) / 256, 256, 0, stream>>>(agg, N3);

    const int nchunks = (E + 63) >> 6;            // one 64-edge chunk per wave
    const int nblocks = (nchunks + 3) / 4;        // 4 waves per block
    attn_kernel<<<nblocks, 256, 0, stream>>>(a_ij, pos, eidx, mask, pro,
                                             W1, b1, W2, b2, Wh, agg, E);

    finalize_kernel<<<(G + 255) / 256, 256, 0, stream>>>(pos, gidx, agg, d_out,
                                                         W1, mask, eidx, G);
}